// Round 6
// baseline (409.988 us; speedup 1.0000x reference)
//
#include <hip/hip_runtime.h>
#include <hip/hip_bf16.h>
#include <cstdint>
#include <cstddef>

#define HH 1024
#define BB 8
#define TT 2048
#define MM (BB*TT)   // 16384
#define CC 64        // wkv chunks
#define LL (TT/CC)   // 32 steps per chunk

typedef __attribute__((ext_vector_type(8))) short bf16x8;
typedef __attribute__((ext_vector_type(4))) float f32x4;

__device__ __forceinline__ unsigned short f2bf(float f) {
  union { float f; unsigned u; } v; v.f = f;
  return (unsigned short)((v.u + 0x7fffu + ((v.u >> 16) & 1u)) >> 16);  // RNE
}
__device__ __forceinline__ float bf2f(unsigned short s) {
  union { float f; unsigned u; } v; v.u = ((unsigned)s) << 16;
  return v.f;
}

__device__ __forceinline__ void load_lds16(const void* g, void* l) {
  __builtin_amdgcn_global_load_lds((const __attribute__((address_space(1))) void*)g,
                                   (__attribute__((address_space(3))) void*)l,
                                   16, 0, 0);
}

// ---------------- fused prep: mix (blocks 0..16383) + weight conv (blocks 16384..20479) ----
__global__ __launch_bounds__(256) void prep_kernel(const float* __restrict__ x,
    const float* __restrict__ tmk, const float* __restrict__ tmv, const float* __restrict__ tmr,
    const float* __restrict__ Wk, const float* __restrict__ Wv,
    const float* __restrict__ Wr, const float* __restrict__ Wo,
    unsigned short* __restrict__ kin, unsigned short* __restrict__ vin,
    unsigned short* __restrict__ rin, unsigned short* __restrict__ Wbf) {
  const int bx = blockIdx.x;
  if (bx >= 16384) {
    const int bl = bx - 16384;
    const int wsel = bl >> 10;
    const int i = ((bl & 1023) * 256 + threadIdx.x) * 4;
    const float* src = wsel == 0 ? Wk : wsel == 1 ? Wv : wsel == 2 ? Wr : Wo;
    const float4 v = *(const float4*)(src + i);
    ushort4 o; o.x = f2bf(v.x); o.y = f2bf(v.y); o.z = f2bf(v.z); o.w = f2bf(v.w);
    *(ushort4*)(Wbf + (size_t)wsel * HH * HH + i) = o;
    return;
  }
  const int gid = bx * 256 + threadIdx.x;
  const size_t e0 = (size_t)gid * 4;
  const int h = (int)(e0 & (HH - 1));
  const int t = (int)((e0 >> 10) & (TT - 1));
  const float4 xv = *(const float4*)(x + e0);
  float4 sv = make_float4(0.f, 0.f, 0.f, 0.f);
  if (t != 0) sv = *(const float4*)(x + e0 - HH);
  const float4 k4 = *(const float4*)(tmk + h);
  const float4 v4 = *(const float4*)(tmv + h);
  const float4 r4 = *(const float4*)(tmr + h);
  ushort4 ko, vo, ro;
  ko.x = f2bf(sv.x + k4.x * (xv.x - sv.x)); ko.y = f2bf(sv.y + k4.y * (xv.y - sv.y));
  ko.z = f2bf(sv.z + k4.z * (xv.z - sv.z)); ko.w = f2bf(sv.w + k4.w * (xv.w - sv.w));
  vo.x = f2bf(sv.x + v4.x * (xv.x - sv.x)); vo.y = f2bf(sv.y + v4.y * (xv.y - sv.y));
  vo.z = f2bf(sv.z + v4.z * (xv.z - sv.z)); vo.w = f2bf(sv.w + v4.w * (xv.w - sv.w));
  ro.x = f2bf(sv.x + r4.x * (xv.x - sv.x)); ro.y = f2bf(sv.y + r4.y * (xv.y - sv.y));
  ro.z = f2bf(sv.z + r4.z * (xv.z - sv.z)); ro.w = f2bf(sv.w + r4.w * (xv.w - sv.w));
  *(ushort4*)(kin + e0) = ko;
  *(ushort4*)(vin + e0) = vo;
  *(ushort4*)(rin + e0) = ro;
}

// ---------------- GEMM core: C[128x128] tile, A[M,K]*B[N,K]^T, bf16 ----------------
// m97 structure: 4 waves 2x2, each wave 64x64 = 4x4 frags of 16x16x32 MFMA.
// LDS: row-major rows of 32 ushorts; slot s (16B) of row r holds k-chunk q = s ^ ((r>>1)&3).
//  - staging: 4 consecutive lanes share a row, q permutes 0..3 -> coalesced 64B; LDS dst is
//    wave-uniform base + lane*16 (global_load_lds constraint).
//  - frag read: bank-start = 16(r&1)+4(fq^((r>>1)&3)); over 16 lanes (fq fixed) each bank
//    group is hit exactly 2x = structural minimum -> conflict-free ds_read_b128.
__device__ __forceinline__ void gemm_core(const unsigned short* __restrict__ Ag,
                                          const unsigned short* __restrict__ Bg,
                                          int m0, int n0,
                                          unsigned short* As, unsigned short* Bs,
                                          f32x4 acc[4][4]) {
  const int tid = threadIdx.x;
  const int lane = tid & 63;
  const int w = tid >> 6;
  const int K = HH;
  const int c0 = tid, c1 = 256 + tid;
  const int r0 = c0 >> 2, q0 = (c0 & 3) ^ ((r0 >> 1) & 3);
  const int r1 = c1 >> 2, q1 = (c1 & 3) ^ ((r1 >> 1) & 3);
  const unsigned short* ga0 = Ag + (size_t)(m0 + r0) * K + q0 * 8;
  const unsigned short* ga1 = Ag + (size_t)(m0 + r1) * K + q1 * 8;
  const unsigned short* gb0 = Bg + (size_t)(n0 + r0) * K + q0 * 8;
  const unsigned short* gb1 = Bg + (size_t)(n0 + r1) * K + q1 * 8;
  unsigned short* la0 = As + (size_t)w * 512;          // wave-uniform base (ushort units)
  unsigned short* la1 = As + 2048 + (size_t)w * 512;
  unsigned short* lb0 = Bs + (size_t)w * 512;
  unsigned short* lb1 = Bs + 2048 + (size_t)w * 512;
  const int wm = w >> 1, wn = w & 1;
  const int fr = lane & 15, fq = lane >> 4;

  for (int kt = 0; kt < K; kt += 32) {
    load_lds16(ga0 + kt, la0);
    load_lds16(ga1 + kt, la1);
    load_lds16(gb0 + kt, lb0);
    load_lds16(gb1 + kt, lb1);
    __syncthreads();
    bf16x8 af[4], bfr[4];
#pragma unroll
    for (int i = 0; i < 4; i++) {
      const int ar = wm * 64 + i * 16 + fr;
      af[i] = *(const bf16x8*)(As + ar * 32 + ((fq ^ ((ar >> 1) & 3)) * 8));
    }
#pragma unroll
    for (int j = 0; j < 4; j++) {
      const int br = wn * 64 + j * 16 + fr;
      bfr[j] = *(const bf16x8*)(Bs + br * 32 + ((fq ^ ((br >> 1) & 3)) * 8));
    }
#pragma unroll
    for (int i = 0; i < 4; i++)
#pragma unroll
      for (int j = 0; j < 4; j++)
        acc[i][j] = __builtin_amdgcn_mfma_f32_16x16x32_bf16(af[i], bfr[j], acc[i][j], 0, 0, 0);
    __syncthreads();
  }
}

// XCD-aware swizzle: x&7 -> xcd stripe of 16 m-tiles; n fast within stripe.
__device__ __forceinline__ void swizzle_mn(int x, int& m0, int& n0) {
  const int xcd = x & 7;
  const int t = x >> 3;
  const int bn = t & 7;
  const int bml = t >> 3;          // 0..15
  m0 = (xcd * 16 + bml) * 128;
  n0 = bn * 128;
}

// z=0: k -> bf16, z=1: v -> bf16, z=2: r -> sigmoid -> bf16
__global__ __launch_bounds__(256) void gemm_kvr(const unsigned short* __restrict__ kin,
    const unsigned short* __restrict__ vin, const unsigned short* __restrict__ rin,
    const unsigned short* __restrict__ Wbf,
    unsigned short* __restrict__ kb, unsigned short* __restrict__ vb,
    unsigned short* __restrict__ rb) {
  __shared__ unsigned short As[128 * 32];
  __shared__ unsigned short Bs[128 * 32];
  const int z = blockIdx.y;
  const unsigned short* Ag = z == 0 ? kin : (z == 1 ? vin : rin);
  const unsigned short* Bg = Wbf + (size_t)z * HH * HH;
  unsigned short* Cg = z == 0 ? kb : (z == 1 ? vb : rb);
  int m0, n0; swizzle_mn(blockIdx.x, m0, n0);
  f32x4 acc[4][4] = {};
  gemm_core(Ag, Bg, m0, n0, As, Bs, acc);
  const int lane = threadIdx.x & 63, w = threadIdx.x >> 6;
  const int wm = w >> 1, wn = w & 1, fr = lane & 15, fq = lane >> 4;
  const bool sig = (z == 2);
#pragma unroll
  for (int i = 0; i < 4; i++)
#pragma unroll
    for (int j = 0; j < 4; j++)
#pragma unroll
      for (int rr = 0; rr < 4; rr++) {
        const int row = m0 + wm * 64 + i * 16 + fq * 4 + rr;
        const int col = n0 + wn * 64 + j * 16 + fr;
        float vv = acc[i][j][rr];
        if (sig) vv = 1.0f / (1.0f + __expf(-vv));
        Cg[(size_t)row * HH + col] = f2bf(vv);
      }
}

// out = rwkv @ Wo^T + bo  (fp32 out)
__global__ __launch_bounds__(256) void gemm_o(const unsigned short* __restrict__ Ag,
    const unsigned short* __restrict__ Bg, const float* __restrict__ bias,
    float* __restrict__ C) {
  __shared__ unsigned short As[128 * 32];
  __shared__ unsigned short Bs[128 * 32];
  int m0, n0; swizzle_mn(blockIdx.x, m0, n0);
  f32x4 acc[4][4] = {};
  gemm_core(Ag, Bg, m0, n0, As, Bs, acc);
  const int lane = threadIdx.x & 63, w = threadIdx.x >> 6;
  const int wm = w >> 1, wn = w & 1, fr = lane & 15, fq = lane >> 4;
#pragma unroll
  for (int i = 0; i < 4; i++)
#pragma unroll
    for (int j = 0; j < 4; j++) {
      const int col = n0 + wn * 64 + j * 16 + fr;
      const float bv = bias[col];
#pragma unroll
      for (int rr = 0; rr < 4; rr++) {
        const int row = m0 + wm * 64 + i * 16 + fq * 4 + rr;
        C[(size_t)row * HH + col] = acc[i][j][rr] + bv;
      }
    }
}

// ---------------- WKV: chunk-parallel scan over T ----------------
__global__ __launch_bounds__(256) void wkv_part(const unsigned short* __restrict__ k,
    const unsigned short* __restrict__ v, const float* __restrict__ tdec,
    float* __restrict__ pnum, float* __restrict__ pden) {
  const int gid = blockIdx.x * 256 + threadIdx.x;   // 0 .. CC*BB*HH-1
  const int h = gid & (HH - 1);
  const int bh = gid & (BB * HH - 1);
  const int b = (gid >> 10) & (BB - 1);
  const int c = gid >> 13;
  const float td = __expf(-__expf(tdec[h]));
  size_t idx = (size_t)b * TT * HH + (size_t)(c * LL) * HH + h;
  float num = 0.f, den = 0.f;
#pragma unroll 8
  for (int i = 0; i < LL; ++i, idx += HH) {
    const float ek = __expf(bf2f(k[idx]));
    const float vt = bf2f(v[idx]);
    num = td * num + ek * vt;
    den = td * den + ek;
  }
  pnum[(size_t)c * (BB * HH) + bh] = num;
  pden[(size_t)c * (BB * HH) + bh] = den;
}

// Inline prefix over earlier chunks (partials are L2-resident; <=63 iters), then stream.
__global__ __launch_bounds__(256) void wkv_final(const unsigned short* __restrict__ k,
    const unsigned short* __restrict__ v, const unsigned short* __restrict__ r,
    const float* __restrict__ tdec, const float* __restrict__ tfst,
    const float* __restrict__ pnum, const float* __restrict__ pden,
    unsigned short* __restrict__ rwkv) {
  const int gid = blockIdx.x * 256 + threadIdx.x;
  const int h = gid & (HH - 1);
  const int bh = gid & (BB * HH - 1);
  const int b = (gid >> 10) & (BB - 1);
  const int c = gid >> 13;
  const float ed = __expf(tdec[h]);
  const float td = __expf(-ed);
  const float tdL = __expf(-ed * (float)LL);         // td^LL exactly
  const float etf = __expf(tfst[h]);
  float num = 0.f, den = 0.f;
  for (int cc = 0; cc < c; ++cc) {                   // c uniform per block
    const size_t o = (size_t)cc * (BB * HH) + bh;
    num = tdL * num + pnum[o];
    den = tdL * den + pden[o];
  }
  size_t idx = (size_t)b * TT * HH + (size_t)(c * LL) * HH + h;
#pragma unroll 4
  for (int i = 0; i < LL; ++i, idx += HH) {
    const float ek = __expf(bf2f(k[idx]));
    const float vt = bf2f(v[idx]);
    const float rt = bf2f(r[idx]);
    const float e = ek * etf;                        // exp(tf + k) = exp(k)*exp(tf)
    const float inv = __builtin_amdgcn_rcpf(den + e);
    const float outv = (num + e * vt) * inv;
    num = td * num + ek * vt;
    den = td * den + ek;
    rwkv[idx] = f2bf(outv * rt);
  }
}

extern "C" void kernel_launch(void* const* d_in, const int* in_sizes, int n_in,
                              void* d_out, int out_size, void* d_ws, size_t ws_size,
                              hipStream_t stream) {
  (void)in_sizes; (void)n_in; (void)out_size; (void)ws_size;
  const float* x    = (const float*)d_in[0];
  const float* tdec = (const float*)d_in[1];
  const float* tfst = (const float*)d_in[2];
  const float* tmk  = (const float*)d_in[3];
  const float* tmv  = (const float*)d_in[4];
  const float* tmr  = (const float*)d_in[5];
  const float* Wk   = (const float*)d_in[6];
  const float* Wv   = (const float*)d_in[7];
  const float* Wr   = (const float*)d_in[8];
  const float* Wo   = (const float*)d_in[9];
  const float* bo   = (const float*)d_in[10];
  float* out = (float*)d_out;

  char* ws = (char*)d_ws;
  const size_t MiB = (size_t)1 << 20;
  unsigned short* Wbf = (unsigned short*)(ws);             //   8 MiB
  unsigned short* kin = (unsigned short*)(ws + 8 * MiB);   //  32 MiB
  unsigned short* vin = (unsigned short*)(ws + 40 * MiB);  //  32 MiB
  unsigned short* rin = (unsigned short*)(ws + 72 * MiB);  //  32 MiB
  unsigned short* rb  = (unsigned short*)(ws + 104 * MiB); //  32 MiB  (peak 136 MiB)
  // k,v bf16 staged in d_out (64 MiB fp32 buffer = 2 x 32 MiB bf16); dead before gemm_o writes.
  unsigned short* kb = (unsigned short*)out;
  unsigned short* vb = kb + (size_t)MM * HH;
  unsigned short* rwkv = kin;                  // kin dead after gemm_kvr
  float* pnum = (float*)(ws + 40 * MiB);       // vin dead after gemm_kvr (2 MiB)
  float* pden = (float*)(ws + 42 * MiB);       // (2 MiB)

  hipLaunchKernelGGL(prep_kernel, dim3(16384 + 4096), dim3(256), 0, stream,
                     x, tmk, tmv, tmr, Wk, Wv, Wr, Wo, kin, vin, rin, Wbf);
  hipLaunchKernelGGL(gemm_kvr, dim3(1024, 3), dim3(256), 0, stream,
                     kin, vin, rin, Wbf, kb, vb, rb);
  hipLaunchKernelGGL(wkv_part, dim3(2048), dim3(256), 0, stream,
                     kb, vb, tdec, pnum, pden);
  hipLaunchKernelGGL(wkv_final, dim3(2048), dim3(256), 0, stream,
                     kb, vb, rb, tdec, tfst, pnum, pden, rwkv);
  hipLaunchKernelGGL(gemm_o, dim3(1024), dim3(256), 0, stream,
                     rwkv, Wbf + (size_t)3 * HH * HH, bo, out);
}